// Round 3
// baseline (66.491 us; speedup 1.0000x reference)
//
#include <hip/hip_runtime.h>

#define B 64
#define C 2048
#define L 1024
#define WCHUNK 256            // w values handled per block
#define NBLK_W (L / WCHUNK)   // 4 -> grid = 64*4 = 256 blocks

__global__ void zero_kernel(float* __restrict__ out) {
    out[0] = 0.0f;
}

__global__ __launch_bounds__(1024)
void RankingLoss_kernel(const float* __restrict__ ranks,
                        const int* __restrict__ labels,
                        const int* __restrict__ ids,   // int32! jax x64-disabled downcasts int64
                        float* __restrict__ out)
{
    __shared__ float s_r[L];
    __shared__ float s_neg[L];   // 1.0f if label != 1 else 0.0f
    __shared__ float s_partial[16];

    const int b  = blockIdx.x / NBLK_W;
    const int wc = blockIdx.x % NBLK_W;
    const int t  = threadIdx.x;

    // Gather r and label flags for this batch into LDS.
    {
        const int id  = ids[t];                 // values < C
        const float r = ranks[b * C + id];
        const int lab = labels[b * C + id];
        s_r[t]   = r;
        s_neg[t] = (lab != 1) ? 1.0f : 0.0f;
    }
    __syncthreads();

    const float rc   = s_r[t];
    const float posc = 1.0f - s_neg[t];

    float acc = 0.0f;
    if (posc != 0.0f) {
        const int w0 = wc * WCHUNK;
        const float base = 0.03f - rc;
        #pragma unroll 8
        for (int i = 0; i < WCHUNK; ++i) {
            const int w = w0 + i;
            const float v = base + s_r[w];          // LDS broadcast reads
            acc += s_neg[w] * fmaxf(v, 0.0f);
        }
    }

    // Wave (64-lane) shuffle reduction.
    #pragma unroll
    for (int off = 32; off > 0; off >>= 1)
        acc += __shfl_down(acc, off, 64);

    const int lane = t & 63;
    const int wave = t >> 6;
    if (lane == 0) s_partial[wave] = acc;
    __syncthreads();

    if (wave == 0) {
        float v = (lane < 16) ? s_partial[lane] : 0.0f;
        #pragma unroll
        for (int off = 8; off > 0; off >>= 1)
            v += __shfl_down(v, off, 64);
        if (lane == 0)
            atomicAdd(out, v * (1.0f / B));
    }
}

extern "C" void kernel_launch(void* const* d_in, const int* in_sizes, int n_in,
                              void* d_out, int out_size, void* d_ws, size_t ws_size,
                              hipStream_t stream) {
    const float* ranks = (const float*)d_in[0];
    const int* labels  = (const int*)d_in[1];
    const int* ids     = (const int*)d_in[2];
    float* out         = (float*)d_out;

    // d_out is re-poisoned to 0xAA before every timed launch; zero it with a
    // tiny kernel on the same stream.
    zero_kernel<<<1, 1, 0, stream>>>(out);

    RankingLoss_kernel<<<B * NBLK_W, 1024, 0, stream>>>(ranks, labels, ids, out);
}

// Round 4
// 65.971 us; speedup vs baseline: 1.0079x; 1.0079x over previous
//
#include <hip/hip_runtime.h>

#define B 64
#define C 2048
#define L 1024
#define WCHUNK 256            // w values per block
#define NBLK_W (L / WCHUNK)   // 4 -> grid = 64*4 = 256 blocks
#define NC 4                  // c values per thread (register blocking)
#define WSUB 64               // w values per thread (WCHUNK / 4 j-groups)

__global__ void zero_kernel(float* __restrict__ out) {
    out[0] = 0.0f;
}

__global__ __launch_bounds__(1024)
void RankingLoss_kernel(const float* __restrict__ ranks,
                        const int* __restrict__ labels,
                        const int* __restrict__ ids,   // int32 (jax x64-disabled)
                        float* __restrict__ out)
{
    // Mask fused into values: non-neg w -> -1e30 (relu kills it),
    // non-pos c -> +1e30 (base = 0.03 - rc = -huge, relu kills the row).
    __shared__ float s_rw[L];    // w-role: r if label!=1 else -1e30
    __shared__ float s_rc[L];    // c-role: r if label==1 else +1e30
    __shared__ float s_partial[16];

    const int b  = blockIdx.x / NBLK_W;
    const int wc = blockIdx.x % NBLK_W;
    const int t  = threadIdx.x;

    // Gather (coalesced on t; ids are sorted so the row gather has locality).
    {
        const int id  = ids[t];
        const float r = ranks[b * C + id];
        const int lab = labels[b * C + id];
        const bool pos = (lab == 1);
        s_rw[t] = pos ? -1e30f : r;
        s_rc[t] = pos ? r : 1e30f;
    }
    __syncthreads();

    const int i = t & 255;        // c-group: owns c = i + 256*k
    const int j = t >> 8;         // w-subchunk: whole wave shares j -> broadcast reads

    float base[NC];
    #pragma unroll
    for (int k = 0; k < NC; ++k)
        base[k] = 0.03f - s_rc[i + 256 * k];

    float acc[NC] = {0.f, 0.f, 0.f, 0.f};
    const int w0 = wc * WCHUNK + j * WSUB;

    #pragma unroll 4
    for (int it = 0; it < WSUB / 4; ++it) {
        // ds_read_b128 broadcast: all 64 lanes read the same address.
        const float4 rw = *(const float4*)&s_rw[w0 + it * 4];
        #pragma unroll
        for (int k = 0; k < NC; ++k) {
            acc[k] += fmaxf(rw.x + base[k], 0.0f);
            acc[k] += fmaxf(rw.y + base[k], 0.0f);
            acc[k] += fmaxf(rw.z + base[k], 0.0f);
            acc[k] += fmaxf(rw.w + base[k], 0.0f);
        }
    }

    float v = (acc[0] + acc[1]) + (acc[2] + acc[3]);

    // Wave (64-lane) shuffle reduction.
    #pragma unroll
    for (int off = 32; off > 0; off >>= 1)
        v += __shfl_down(v, off, 64);

    const int lane = t & 63;
    const int wave = t >> 6;
    if (lane == 0) s_partial[wave] = v;
    __syncthreads();

    if (wave == 0) {
        float s = (lane < 16) ? s_partial[lane] : 0.0f;
        #pragma unroll
        for (int off = 8; off > 0; off >>= 1)
            s += __shfl_down(s, off, 64);
        if (lane == 0)
            atomicAdd(out, s * (1.0f / B));
    }
}

extern "C" void kernel_launch(void* const* d_in, const int* in_sizes, int n_in,
                              void* d_out, int out_size, void* d_ws, size_t ws_size,
                              hipStream_t stream) {
    const float* ranks = (const float*)d_in[0];
    const int* labels  = (const int*)d_in[1];
    const int* ids     = (const int*)d_in[2];
    float* out         = (float*)d_out;

    zero_kernel<<<1, 1, 0, stream>>>(out);
    RankingLoss_kernel<<<B * NBLK_W, 1024, 0, stream>>>(ranks, labels, ids, out);
}

// Round 5
// 64.463 us; speedup vs baseline: 1.0315x; 1.0234x over previous
//
#include <hip/hip_runtime.h>

#define B 64
#define C 2048
#define L 1024
#define WCHUNK 256            // w values per block
#define NBLK_W (L / WCHUNK)   // 4 -> grid = 64*4 = 256 blocks
#define NC 4                  // c values per thread (register blocking)
#define WSUB 64               // w values per thread
#define NBLOCKS (B * NBLK_W)  // 256 partials

__global__ __launch_bounds__(1024)
void rank_partial_kernel(const float* __restrict__ ranks,
                         const int* __restrict__ labels,
                         const int* __restrict__ ids,   // int32 (jax x64-disabled)
                         float* __restrict__ partials)
{
    // Mask fused into values: non-neg w -> -1e30 (relu kills it),
    // non-pos c -> +1e30 (base = 0.03 - rc = -huge, relu kills the row).
    __shared__ float s_rw[L];    // w-role: r if label!=1 else -1e30
    __shared__ float s_rc[L];    // c-role: r if label==1 else +1e30
    __shared__ float s_partial[16];

    const int b  = blockIdx.x / NBLK_W;
    const int wc = blockIdx.x % NBLK_W;
    const int t  = threadIdx.x;

    {
        const int id  = ids[t];
        const float r = ranks[b * C + id];
        const int lab = labels[b * C + id];
        const bool pos = (lab == 1);
        s_rw[t] = pos ? -1e30f : r;
        s_rc[t] = pos ? r : 1e30f;
    }
    __syncthreads();

    const int i = t & 255;        // c-group: owns c = i + 256*k
    const int j = t >> 8;         // wave-uniform w-subchunk -> pure LDS broadcast

    float base[NC];
    #pragma unroll
    for (int k = 0; k < NC; ++k)
        base[k] = 0.03f - s_rc[i + 256 * k];

    float acc[NC] = {0.f, 0.f, 0.f, 0.f};
    const int w0 = wc * WCHUNK + j * WSUB;

    #pragma unroll 4
    for (int it = 0; it < WSUB / 4; ++it) {
        const float4 rw = *(const float4*)&s_rw[w0 + it * 4];   // ds_read_b128 broadcast
        #pragma unroll
        for (int k = 0; k < NC; ++k) {
            acc[k] += fmaxf(rw.x + base[k], 0.0f);
            acc[k] += fmaxf(rw.y + base[k], 0.0f);
            acc[k] += fmaxf(rw.z + base[k], 0.0f);
            acc[k] += fmaxf(rw.w + base[k], 0.0f);
        }
    }

    float v = (acc[0] + acc[1]) + (acc[2] + acc[3]);

    #pragma unroll
    for (int off = 32; off > 0; off >>= 1)
        v += __shfl_down(v, off, 64);

    const int lane = t & 63;
    const int wave = t >> 6;
    if (lane == 0) s_partial[wave] = v;
    __syncthreads();

    if (wave == 0) {
        float s = (lane < 16) ? s_partial[lane] : 0.0f;
        #pragma unroll
        for (int off = 8; off > 0; off >>= 1)
            s += __shfl_down(s, off, 64);
        if (lane == 0)
            partials[blockIdx.x] = s;   // plain store, overwrites poison
    }
}

__global__ __launch_bounds__(64)
void rank_final_kernel(const float* __restrict__ partials,
                       float* __restrict__ out)
{
    const int lane = threadIdx.x;   // 64 lanes, 4 partials each
    float s = 0.0f;
    #pragma unroll
    for (int k = 0; k < NBLOCKS / 64; ++k)
        s += partials[lane + 64 * k];
    #pragma unroll
    for (int off = 32; off > 0; off >>= 1)
        s += __shfl_down(s, off, 64);
    if (lane == 0)
        out[0] = s * (1.0f / B);     // plain store, no zeroing pass needed
}

extern "C" void kernel_launch(void* const* d_in, const int* in_sizes, int n_in,
                              void* d_out, int out_size, void* d_ws, size_t ws_size,
                              hipStream_t stream) {
    const float* ranks = (const float*)d_in[0];
    const int* labels  = (const int*)d_in[1];
    const int* ids     = (const int*)d_in[2];
    float* out         = (float*)d_out;
    float* partials    = (float*)d_ws;

    rank_partial_kernel<<<NBLOCKS, 1024, 0, stream>>>(ranks, labels, ids, partials);
    rank_final_kernel<<<1, 64, 0, stream>>>(partials, out);
}